// Round 1
// baseline (299.363 us; speedup 1.0000x reference)
//
#include <hip/hip_runtime.h>

// arbLoss: -(dirichlet + eta*recon + theta*avg)
//   dirichlet = sum(xn * (L@xn))   <- bf16 MFMA GEMM, L read exactly once
//   avg       = n/(n-1)*sum(xn^2) - 1/(n-1)*sum(colsum^2)
//   recon     = sum((xn[know]-out_k_init)^2)
// inputs: 0:x[N,D] f32  1:L[N,N] f32  2:mean[D] f32  3:out_k_init[K,D] f32
//         4:know_mask[K] int  5:theta f32  6:eta f32     out: scalar f32

#define NN    10000
#define DD    256
#define NPADK 10048   // 157*64, k-padded length for xnT
#define BM    128
#define BK    64
#define CK    512     // K-chunk per block
#define NMB   79      // ceil(10000/128)
#define NKC   20      // ceil(10048/512)

typedef float  f32x4 __attribute__((ext_vector_type(4)));
typedef short  s16x8 __attribute__((ext_vector_type(8)));
typedef unsigned int u32x4 __attribute__((ext_vector_type(4)));

__device__ __forceinline__ unsigned short f2bf(float f) {
    union { float f; unsigned u; } c; c.f = f;
    unsigned u = c.u;
    u += 0x7fffu + ((u >> 16) & 1u);   // round-to-nearest-even
    return (unsigned short)(u >> 16);
}

// ---------------------------------------------------------------------------
// prep: xnT_sw[f][k] = bf16(xn[k ^ ((f&7)<<3)][f])  (pre-swizzled transpose,
// pads k in [NN,NPADK) with 0), plus colsum[f] and sum(xn^2) accumulation.
// acc layout (f32): [0]=dirichlet [1]=ss [2]=recon [3]=pad [4..259]=colsum
// ---------------------------------------------------------------------------
__global__ __launch_bounds__(256) void prep_kernel(const float* __restrict__ x,
                                                   const float* __restrict__ mean,
                                                   unsigned short* __restrict__ xnT,
                                                   float* __restrict__ acc) {
    __shared__ unsigned short xs[64][258];   // stride 258 -> conflict-free col reads
    __shared__ float red[4];
    const int t  = threadIdx.x;              // 0..255 == column f
    const int i0 = blockIdx.x * 64;
    const float mn = mean[t];
    float css = 0.f, ss = 0.f;
    for (int ii = 0; ii < 64; ++ii) {
        const int i = i0 + ii;
        float v = 0.f;
        if (i < NN) v = x[(size_t)i * DD + t] - mn;
        css += v; ss += v * v;
        xs[ii][t] = f2bf(v);
    }
    atomicAdd(&acc[4 + t], css);
#pragma unroll
    for (int off = 32; off > 0; off >>= 1) ss += __shfl_xor(ss, off);
    const int lane = t & 63, wid = t >> 6;
    if (lane == 0) red[wid] = ss;
    __syncthreads();
    if (t == 0) atomicAdd(&acc[1], red[0] + red[1] + red[2] + red[3]);
    // transposed + swizzled write (coalesced along i)
    const int ii = t & 63;
    const int fb = t >> 6;
    for (int p = 0; p < 64; ++p) {
        const int f  = p * 4 + fb;
        const int sw = (f & 7) << 3;
        xnT[(size_t)f * NPADK + i0 + ii] = xs[ii ^ sw][f];
    }
}

// ---------------------------------------------------------------------------
// recon: sum((x[know]-mean - out_k_init)^2)
// ---------------------------------------------------------------------------
__global__ __launch_bounds__(256) void recon_kernel(const float* __restrict__ x,
                                                    const float* __restrict__ mean,
                                                    const float* __restrict__ oki,
                                                    const int* __restrict__ know,
                                                    int K, float* __restrict__ acc) {
    __shared__ float red[4];
    const int t = threadIdx.x;
    const float mn = mean[t];
    float s = 0.f;
    for (int b = blockIdx.x; b < K; b += gridDim.x) {
        const int idx = know[b];
        const float v = x[(size_t)idx * DD + t] - mn - oki[(size_t)b * DD + t];
        s += v * v;
    }
#pragma unroll
    for (int off = 32; off > 0; off >>= 1) s += __shfl_xor(s, off);
    const int lane = t & 63, wid = t >> 6;
    if (lane == 0) red[wid] = s;
    __syncthreads();
    if (t == 0) atomicAdd(&acc[2], red[0] + red[1] + red[2] + red[3]);
}

// ---------------------------------------------------------------------------
// gemm: per block (mb,kc): y_part[128,256] = L[rows, kchunk] @ xn[kchunk, 256]
// in bf16 MFMA, then partial dot with exact f32 xn -> atomicAdd(acc[0]).
// LDS 48KB (3 blocks/CU). XOR-swizzled tiles, conflict-free ds_read_b128.
// ---------------------------------------------------------------------------
__global__ __launch_bounds__(512) void gemm_kernel(const float* __restrict__ L,
                                                   const float* __restrict__ x,
                                                   const float* __restrict__ mean,
                                                   const unsigned short* __restrict__ xnT,
                                                   float* __restrict__ acc) {
    __shared__ __align__(16) unsigned short As[BM * BK];  // swizzled L tile (bf16)
    __shared__ __align__(16) unsigned short Bs[DD * BK];  // swizzled xnT tile
    const int tid  = threadIdx.x;
    const int lane = tid & 63;
    const int wid  = tid >> 6;          // 0..7
    const int wr   = wid >> 2;          // 0..1 : 64-row slab
    const int wc   = wid & 3;           // 0..3 : 64-col slab
    const int mb   = blockIdx.x;
    const int kc   = blockIdx.y;
    const int row0 = mb * BM;
    const int k0b  = kc * CK;
    const int rem  = NPADK - k0b;
    const int ksteps = (rem < CK ? rem : CK) >> 6;

    f32x4 acc4[4][4] = {};

    // A staging: thread -> (row, 16-wide k segment)
    const int ar   = tid >> 2;                  // 0..127
    const int ak   = (tid & 3) << 4;            // 0,16,32,48
    const int grow = row0 + ar;
    const unsigned aswz  = (unsigned)((ar & 7) << 4);
    const unsigned abyte = (unsigned)(ar * (BK * 2) + ak * 2);
    char* AsB = (char*)As;
    char* BsB = (char*)Bs;
    // B staging (global_load_lds): wave fills 1KB chunks, lane -> 16B
    const int bn  = lane >> 3;                  // row within 8-row chunk
    const int bko = (lane & 7) << 3;            // k element offset

    for (int s = 0; s < ksteps; ++s) {
        const int k0 = k0b + (s << 6);
        if (s) __syncthreads();                 // previous compute done
        // ---- stage B: async global->LDS (source pre-swizzled, LDS linear) ----
#pragma unroll
        for (int t2 = 0; t2 < 4; ++t2) {
            const int chunk = wid * 4 + t2;     // 0..31
            const int nrow  = chunk * 8 + bn;   // 0..255
            const unsigned short* src = xnT + (size_t)nrow * NPADK + k0 + bko;
            __builtin_amdgcn_global_load_lds(
                (const __attribute__((address_space(1))) void*)src,
                (__attribute__((address_space(3))) void*)(BsB + chunk * 1024),
                16, 0, 0);
        }
        // ---- stage A: f32 load -> bf16 -> swizzled ds_write ----
        float v[16];
        const int kg = k0 + ak;
        if (grow < NN) {
            const float* Lr = L + (size_t)grow * NN + kg;
            if (kg + 16 <= NN) {
                const float4* Lp = (const float4*)Lr;
#pragma unroll
                for (int q = 0; q < 4; ++q) {
                    const float4 p = Lp[q];
                    v[4*q+0] = p.x; v[4*q+1] = p.y; v[4*q+2] = p.z; v[4*q+3] = p.w;
                }
            } else {
#pragma unroll
                for (int e = 0; e < 16; ++e) v[e] = (kg + e < NN) ? Lr[e] : 0.f;
            }
        } else {
#pragma unroll
            for (int e = 0; e < 16; ++e) v[e] = 0.f;
        }
        unsigned w[8];
#pragma unroll
        for (int e = 0; e < 8; ++e)
            w[e] = (unsigned)f2bf(v[2*e]) | ((unsigned)f2bf(v[2*e+1]) << 16);
        u32x4 lo = { w[0], w[1], w[2], w[3] };
        u32x4 hi = { w[4], w[5], w[6], w[7] };
        *(u32x4*)(AsB + ( abyte        ^ aswz)) = lo;
        *(u32x4*)(AsB + ((abyte + 16u) ^ aswz)) = hi;
        __syncthreads();                        // staging visible (vmcnt+lgkm drain)
        // ---- compute: 2 x (8 ds_read_b128 + 16 MFMA) ----
#pragma unroll
        for (int kk = 0; kk < 2; ++kk) {
            const int kbase = kk * 32 + ((lane >> 4) << 3);
            s16x8 af[4], bf[4];
#pragma unroll
            for (int mi = 0; mi < 4; ++mi) {
                const int r = wr * 64 + mi * 16 + (lane & 15);
                const unsigned off = (unsigned)(r * (BK*2) + kbase * 2) ^ (unsigned)((r & 7) << 4);
                af[mi] = *(const s16x8*)(AsB + off);
            }
#pragma unroll
            for (int ni = 0; ni < 4; ++ni) {
                const int n = wc * 64 + ni * 16 + (lane & 15);
                const unsigned off = (unsigned)(n * (BK*2) + kbase * 2) ^ (unsigned)((n & 7) << 4);
                bf[ni] = *(const s16x8*)(BsB + off);
            }
#pragma unroll
            for (int mi = 0; mi < 4; ++mi)
#pragma unroll
                for (int ni = 0; ni < 4; ++ni)
                    acc4[mi][ni] = __builtin_amdgcn_mfma_f32_16x16x32_bf16(
                        af[mi], bf[ni], acc4[mi][ni], 0, 0, 0);
        }
    }

    // ---- epilogue: partial dot with exact f32 xn; one atomic per wave ----
    float sdot = 0.f;
    const int colb = wc * 64 + (lane & 15);
    float mn[4];
#pragma unroll
    for (int ni = 0; ni < 4; ++ni) mn[ni] = mean[colb + ni * 16];
#pragma unroll
    for (int mi = 0; mi < 4; ++mi) {
        const int rb = row0 + wr * 64 + mi * 16 + ((lane >> 4) << 2);
#pragma unroll
        for (int j = 0; j < 4; ++j) {
            const int r = rb + j;
            if (r < NN) {
                const float* xr = x + (size_t)r * DD + colb;
#pragma unroll
                for (int ni = 0; ni < 4; ++ni)
                    sdot += (xr[ni * 16] - mn[ni]) * acc4[mi][ni][j];
            }
        }
    }
#pragma unroll
    for (int off = 32; off > 0; off >>= 1) sdot += __shfl_xor(sdot, off);
    if (lane == 0) atomicAdd(&acc[0], sdot);
}

// ---------------------------------------------------------------------------
// finalize: out = -(dir + eta*recon + theta*(n/(n-1)*ss - colsq/(n-1)))
// ---------------------------------------------------------------------------
__global__ __launch_bounds__(256) void fin_kernel(const float* __restrict__ acc,
                                                  const float* __restrict__ theta,
                                                  const float* __restrict__ eta,
                                                  float* __restrict__ out) {
    __shared__ float red[4];
    const int t = threadIdx.x;
    const float c = acc[4 + t];
    float s = c * c;
#pragma unroll
    for (int off = 32; off > 0; off >>= 1) s += __shfl_xor(s, off);
    const int lane = t & 63, wid = t >> 6;
    if (lane == 0) red[wid] = s;
    __syncthreads();
    if (t == 0) {
        const float colsq = red[0] + red[1] + red[2] + red[3];
        const float n = (float)NN;
        const float avg = (n / (n - 1.f)) * acc[1] - colsq / (n - 1.f);
        out[0] = -(acc[0] + eta[0] * acc[2] + theta[0] * avg);
    }
}

extern "C" void kernel_launch(void* const* d_in, const int* in_sizes, int n_in,
                              void* d_out, int out_size, void* d_ws, size_t ws_size,
                              hipStream_t stream) {
    const float* x     = (const float*)d_in[0];
    const float* L     = (const float*)d_in[1];
    const float* mean  = (const float*)d_in[2];
    const float* oki   = (const float*)d_in[3];
    const int*   know  = (const int*)d_in[4];
    const float* theta = (const float*)d_in[5];
    const float* eta   = (const float*)d_in[6];
    float* out = (float*)d_out;

    unsigned short* xnT = (unsigned short*)d_ws;
    float* acc = (float*)((char*)d_ws + (size_t)DD * NPADK * 2);
    const int K = in_sizes[4];

    hipMemsetAsync(acc, 0, 260 * sizeof(float), stream);
    hipLaunchKernelGGL(prep_kernel,  dim3(NPADK / 64), dim3(256), 0, stream, x, mean, xnT, acc);
    hipLaunchKernelGGL(recon_kernel, dim3(256),        dim3(256), 0, stream, x, mean, oki, know, K, acc);
    hipLaunchKernelGGL(gemm_kernel,  dim3(NMB, NKC),   dim3(512), 0, stream, L, x, mean, xnT, acc);
    hipLaunchKernelGGL(fin_kernel,   dim3(1),          dim3(256), 0, stream, acc, theta, eta, out);
}

// Round 2
// 285.293 us; speedup vs baseline: 1.0493x; 1.0493x over previous
//
#include <hip/hip_runtime.h>

// arbLoss: -(dirichlet + eta*recon + theta*avg)
//   dirichlet = sum(xn * (L@xn))   <- bf16 MFMA GEMM, L read exactly once
//   avg       = n/(n-1)*sum(xn^2) - 1/(n-1)*sum(colsum^2)
//   recon     = sum((xn[know]-out_k_init)^2)
// inputs: 0:x[N,D] f32  1:L[N,N] f32  2:mean[D] f32  3:out_k_init[K,D] f32
//         4:know_mask[K] int  5:theta f32  6:eta f32     out: scalar f32

#define NN    10000
#define DD    256
#define CK    1024    // K-chunk per block
#define BKF   256     // fetch granularity (1KB/row of L per fetch)
#define NPADK 10240   // 10*CK
#define NKB   160     // 64-wide k-blocks in padded K
#define NMB   79      // ceil(10000/128)
#define NKC   10      // NPADK/CK

typedef float  f32x4 __attribute__((ext_vector_type(4)));
typedef short  s16x8 __attribute__((ext_vector_type(8)));
typedef unsigned int u32x4 __attribute__((ext_vector_type(4)));

__device__ __forceinline__ unsigned short f2bf(float f) {
    union { float f; unsigned u; } c; c.f = f;
    unsigned u = c.u;
    u += 0x7fffu + ((u >> 16) & 1u);   // round-to-nearest-even
    return (unsigned short)(u >> 16);
}

// ---------------------------------------------------------------------------
// prep: xnG = bf16 xn in MFMA-fragment-major layout:
//   word16 index g within k-block kb: g = (nhi*2 + kk)*64 + lane
//   data[j] = xn[kb*64 + kk*32 + (lane>>4)*8 + j][nhi*16 + (lane&15)]
// so a B-fragment load in the GEMM is one coalesced 16B/lane global load.
// Also: colsum[f] -> acc[4+f], sum(xn^2) -> acc[1].
// acc layout (f32): [0]=dirichlet [1]=ss [2]=recon [3]=pad [4..259]=colsum
// ---------------------------------------------------------------------------
__global__ __launch_bounds__(256) void prep_kernel(const float* __restrict__ x,
                                                   const float* __restrict__ mean,
                                                   unsigned short* __restrict__ xnG,
                                                   float* __restrict__ acc) {
    __shared__ unsigned short xs[64][258];
    __shared__ float red[4];
    const int t  = threadIdx.x;              // 0..255 == column
    const int kb = blockIdx.x;               // k-block (64 rows of x)
    const int i0 = kb * 64;
    const float mn = mean[t];
    float css = 0.f, ss = 0.f;
    for (int ii = 0; ii < 64; ++ii) {
        const int i = i0 + ii;
        float v = 0.f;
        if (i < NN) v = x[(size_t)i * DD + t] - mn;
        css += v; ss += v * v;
        xs[ii][t] = f2bf(v);
    }
    atomicAdd(&acc[4 + t], css);
#pragma unroll
    for (int off = 32; off > 0; off >>= 1) ss += __shfl_xor(ss, off);
    if ((t & 63) == 0) red[t >> 6] = ss;
    __syncthreads();                         // xs + red ready
    if (t == 0) atomicAdd(&acc[1], red[0] + red[1] + red[2] + red[3]);
    // fragment-major write: thread t writes words g = p*256+t (coalesced)
#pragma unroll
    for (int p = 0; p < 8; ++p) {
        const int g    = p * 256 + t;
        const int lane = g & 63;
        const int kk   = (g >> 6) & 1;
        const int nhi  = g >> 7;
        const int n    = nhi * 16 + (lane & 15);
        const int kloc = kk * 32 + (lane >> 4) * 8;
        unsigned short w[8];
#pragma unroll
        for (int j = 0; j < 8; ++j) w[j] = xs[kloc + j][n];
        *(s16x8*)(xnG + ((size_t)kb * 2048 + g) * 8) = *(const s16x8*)w;
    }
}

// ---------------------------------------------------------------------------
// recon: sum((x[know]-mean - out_k_init)^2)
// ---------------------------------------------------------------------------
__global__ __launch_bounds__(256) void recon_kernel(const float* __restrict__ x,
                                                    const float* __restrict__ mean,
                                                    const float* __restrict__ oki,
                                                    const int* __restrict__ know,
                                                    int K, float* __restrict__ acc) {
    __shared__ float red[4];
    const int t = threadIdx.x;
    const float mn = mean[t];
    float s = 0.f;
    for (int b = blockIdx.x; b < K; b += gridDim.x) {
        const int idx = know[b];
        const float v = x[(size_t)idx * DD + t] - mn - oki[(size_t)b * DD + t];
        s += v * v;
    }
#pragma unroll
    for (int off = 32; off > 0; off >>= 1) s += __shfl_xor(s, off);
    if ((t & 63) == 0) red[t >> 6] = s;
    __syncthreads();
    if (t == 0) atomicAdd(&acc[2], red[0] + red[1] + red[2] + red[3]);
}

// ---------------------------------------------------------------------------
// gemm: block (mb,kc): Ypart[128,256] = L[rows, kchunk] @ xn[kchunk, :] in bf16
// MFMA, then partial dot with f32 xn -> atomicAdd(acc[0]).
//  - A (L) reg-staged f32: 1KB-contiguous per row per fetch (DRAM page
//    locality), issued at END of previous compute phase -> in flight across
//    the barrier; converted to bf16 into swizzled LDS [128][256] (64KB).
//  - B fragments straight from xnG (L2/LLC-hot) into regs, no LDS.
//  - 8 waves = 8 column slabs (32 cols each): no duplicated B reads.
// ---------------------------------------------------------------------------
__global__ __launch_bounds__(512) void gemm_kernel(const float* __restrict__ L,
                                                   const float* __restrict__ x,
                                                   const float* __restrict__ mean,
                                                   const unsigned short* __restrict__ xnG,
                                                   float* __restrict__ acc) {
    __shared__ __align__(16) unsigned short As[128 * 256];  // 64KB swizzled bf16
    const int tid  = threadIdx.x;
    const int lane = tid & 63;
    const int wid  = tid >> 6;          // 0..7 : column slab (32 cols)
    const int mb   = blockIdx.x;
    const int kc   = blockIdx.y;
    const int row0 = mb * 128;

    f32x4 acc4[8][2] = {};

    // A staging geometry: thread -> (row ar, 64-col quarter acq), 256B/lane
    const int ar   = tid >> 2;              // 0..127
    const int acq  = tid & 3;               // col quarter (64 floats)
    const int grow = row0 + ar;
    const unsigned swz   = (unsigned)((ar & 7) << 4);
    const unsigned abase = (unsigned)(ar * 512 + acq * 128);
    char* AsB = (char*)As;
    float va[64];

    auto issueA = [&](int f) {
        const int kg0 = kc * CK + f * BKF + acq * 64;
        if (grow < NN) {
            const float* Lr = L + (size_t)grow * NN + kg0;
            if (kg0 + 64 <= NN) {
#pragma unroll
                for (int q = 0; q < 16; ++q)
                    *(f32x4*)&va[q * 4] = *(const f32x4*)(Lr + q * 4);
            } else {
#pragma unroll
                for (int e = 0; e < 64; ++e) va[e] = (kg0 + e < NN) ? Lr[e] : 0.f;
            }
        } else {
#pragma unroll
            for (int e = 0; e < 64; ++e) va[e] = 0.f;
        }
    };

    issueA(0);
    for (int f = 0; f < 4; ++f) {
        if (f) __syncthreads();             // everyone done reading As
        // convert (compiler waits va's vmcnt here) + swizzled LDS store
#pragma unroll
        for (int s = 0; s < 8; ++s) {
            unsigned wv[4];
#pragma unroll
            for (int e = 0; e < 4; ++e) {
                const int b = s * 8 + e * 2;
                wv[e] = (unsigned)f2bf(va[b]) | ((unsigned)f2bf(va[b + 1]) << 16);
            }
            *(u32x4*)(AsB + ((abase + s * 16u) ^ swz)) = *(const u32x4*)wv;
        }
        __syncthreads();                    // As ready
        const int kbB = kc * 16 + f * 4;
#pragma unroll
        for (int ks = 0; ks < 4; ++ks) {
            const int kb = kbB + ks;
#pragma unroll
            for (int kk = 0; kk < 2; ++kk) {
                s16x8 bfr[2];
#pragma unroll
                for (int ni = 0; ni < 2; ++ni) {
                    const int nhi = wid * 2 + ni;
                    bfr[ni] = *(const s16x8*)(xnG +
                        ((size_t)(kb * 32 + nhi * 2 + kk) * 64 + lane) * 8);
                }
#pragma unroll
                for (int mi = 0; mi < 8; ++mi) {
                    const int r = mi * 16 + (lane & 15);
                    const unsigned off =
                        (unsigned)(r * 512 + ks * 128 + kk * 64 + ((lane >> 4) << 4))
                        ^ (unsigned)((r & 7) << 4);
                    const s16x8 af = *(const s16x8*)(AsB + off);
#pragma unroll
                    for (int ni = 0; ni < 2; ++ni)
                        acc4[mi][ni] = __builtin_amdgcn_mfma_f32_16x16x32_bf16(
                            af, bfr[ni], acc4[mi][ni], 0, 0, 0);
                }
            }
        }
        if (f < 3) issueA(f + 1);           // next fetch in flight across barrier
    }

    // ---- epilogue: partial dot with exact f32 xn; one atomic per wave ----
    float sdot = 0.f;
    const int c0 = wid * 32 + (lane & 15);
    const float mn0 = mean[c0], mn1 = mean[c0 + 16];
#pragma unroll
    for (int mi = 0; mi < 8; ++mi) {
        const int rb = row0 + mi * 16 + ((lane >> 4) << 2);
#pragma unroll
        for (int j = 0; j < 4; ++j) {
            const int r = rb + j;
            if (r < NN) {
                const float* xr = x + (size_t)r * DD + c0;
                sdot += (xr[0]  - mn0) * acc4[mi][0][j]
                      + (xr[16] - mn1) * acc4[mi][1][j];
            }
        }
    }
#pragma unroll
    for (int off = 32; off > 0; off >>= 1) sdot += __shfl_xor(sdot, off);
    if (lane == 0) atomicAdd(&acc[0], sdot);
}

// ---------------------------------------------------------------------------
// finalize: out = -(dir + eta*recon + theta*(n/(n-1)*ss - colsq/(n-1)))
// ---------------------------------------------------------------------------
__global__ __launch_bounds__(256) void fin_kernel(const float* __restrict__ acc,
                                                  const float* __restrict__ theta,
                                                  const float* __restrict__ eta,
                                                  float* __restrict__ out) {
    __shared__ float red[4];
    const int t = threadIdx.x;
    const float c = acc[4 + t];
    float s = c * c;
#pragma unroll
    for (int off = 32; off > 0; off >>= 1) s += __shfl_xor(s, off);
    if ((t & 63) == 0) red[t >> 6] = s;
    __syncthreads();
    if (t == 0) {
        const float colsq = red[0] + red[1] + red[2] + red[3];
        const float n = (float)NN;
        const float avg = (n / (n - 1.f)) * acc[1] - colsq / (n - 1.f);
        out[0] = -(acc[0] + eta[0] * acc[2] + theta[0] * avg);
    }
}

extern "C" void kernel_launch(void* const* d_in, const int* in_sizes, int n_in,
                              void* d_out, int out_size, void* d_ws, size_t ws_size,
                              hipStream_t stream) {
    const float* x     = (const float*)d_in[0];
    const float* L     = (const float*)d_in[1];
    const float* mean  = (const float*)d_in[2];
    const float* oki   = (const float*)d_in[3];
    const int*   know  = (const int*)d_in[4];
    const float* theta = (const float*)d_in[5];
    const float* eta   = (const float*)d_in[6];
    float* out = (float*)d_out;

    unsigned short* xnG = (unsigned short*)d_ws;
    float* acc = (float*)((char*)d_ws + (size_t)NKB * 2048 * 16);  // 5.24MB
    const int K = in_sizes[4];

    hipMemsetAsync(acc, 0, 260 * sizeof(float), stream);
    hipLaunchKernelGGL(prep_kernel,  dim3(NKB),      dim3(256), 0, stream, x, mean, xnG, acc);
    hipLaunchKernelGGL(recon_kernel, dim3(256),      dim3(256), 0, stream, x, mean, oki, know, K, acc);
    hipLaunchKernelGGL(gemm_kernel,  dim3(NMB, NKC), dim3(512), 0, stream, L, x, mean, xnG, acc);
    hipLaunchKernelGGL(fin_kernel,   dim3(1),        dim3(256), 0, stream, acc, theta, eta, out);
}

// Round 3
// 269.644 us; speedup vs baseline: 1.1102x; 1.0580x over previous
//
#include <hip/hip_runtime.h>

// arbLoss: -(dirichlet + eta*recon + theta*avg)
//   dirichlet = sum(xn * (L@xn))   <- bf16 MFMA GEMM, L read exactly once
//   avg       = n/(n-1)*sum(xn^2) - 1/(n-1)*sum(colsum^2)
//   recon     = sum((xn[know]-out_k_init)^2)
// inputs: 0:x[N,D] f32  1:L[N,N] f32  2:mean[D] f32  3:out_k_init[K,D] f32
//         4:know_mask[K] int  5:theta f32  6:eta f32     out: scalar f32
//
// GEMM design (R3): vmem-free compute phases + raw s_barrier (no vmcnt drain)
// so A/B prefetch stays in flight across barriers; all vmem waits are
// compiler-counted register deps. LDS = double-buffered bf16 A only (32KB).

#define NN    10000
#define DD    256
#define NSTEP 10      // K-steps (64 wide) per block
#define CK    640     // NSTEP*64
#define NKC   16      // K chunks: 16*640 = 10240
#define NMB   79      // ceil(10000/128)
#define NPADK 10240
#define NKB   160     // 64-row k-blocks in padded K (prep grid)

typedef float  f32x4 __attribute__((ext_vector_type(4)));
typedef short  s16x8 __attribute__((ext_vector_type(8)));
typedef unsigned int u32x4 __attribute__((ext_vector_type(4)));

__device__ __forceinline__ unsigned short f2bf(float f) {
    union { float f; unsigned u; } c; c.f = f;
    unsigned u = c.u;
    u += 0x7fffu + ((u >> 16) & 1u);   // round-to-nearest-even
    return (unsigned short)(u >> 16);
}

// ---------------------------------------------------------------------------
// prep: xnG = bf16 xn in MFMA-fragment-major layout (16B frag per lane):
//   frag g in k-block kb: g = (nhi*2 + kk)*64 + lane
//   data[j] = xn[kb*64 + kk*32 + (lane>>4)*8 + j][nhi*16 + (lane&15)]
// Also: colsum[f] -> acc[4+f], sum(xn^2) -> acc[1].
// acc layout (f32): [0]=dirichlet [1]=ss [2]=recon [3]=pad [4..259]=colsum
// ---------------------------------------------------------------------------
__global__ __launch_bounds__(256) void prep_kernel(const float* __restrict__ x,
                                                   const float* __restrict__ mean,
                                                   unsigned short* __restrict__ xnG,
                                                   float* __restrict__ acc) {
    __shared__ unsigned short xs[64][258];
    __shared__ float red[4];
    const int t  = threadIdx.x;              // 0..255 == column
    const int kb = blockIdx.x;               // k-block (64 rows of x)
    const int i0 = kb * 64;
    const float mn = mean[t];
    float css = 0.f, ss = 0.f;
    for (int ii = 0; ii < 64; ++ii) {
        const int i = i0 + ii;
        float v = 0.f;
        if (i < NN) v = x[(size_t)i * DD + t] - mn;
        css += v; ss += v * v;
        xs[ii][t] = f2bf(v);
    }
    atomicAdd(&acc[4 + t], css);
#pragma unroll
    for (int off = 32; off > 0; off >>= 1) ss += __shfl_xor(ss, off);
    if ((t & 63) == 0) red[t >> 6] = ss;
    __syncthreads();                         // xs + red ready
    if (t == 0) atomicAdd(&acc[1], red[0] + red[1] + red[2] + red[3]);
#pragma unroll
    for (int p = 0; p < 8; ++p) {
        const int g    = p * 256 + t;
        const int lane = g & 63;
        const int kk   = (g >> 6) & 1;
        const int nhi  = g >> 7;
        const int n    = nhi * 16 + (lane & 15);
        const int kloc = kk * 32 + (lane >> 4) * 8;
        unsigned short w[8];
#pragma unroll
        for (int j = 0; j < 8; ++j) w[j] = xs[kloc + j][n];
        *(s16x8*)(xnG + ((size_t)kb * 2048 + g) * 8) = *(const s16x8*)w;
    }
}

// ---------------------------------------------------------------------------
// recon: sum((x[know]-mean - out_k_init)^2)
// ---------------------------------------------------------------------------
__global__ __launch_bounds__(256) void recon_kernel(const float* __restrict__ x,
                                                    const float* __restrict__ mean,
                                                    const float* __restrict__ oki,
                                                    const int* __restrict__ know,
                                                    int K, float* __restrict__ acc) {
    __shared__ float red[4];
    const int t = threadIdx.x;
    const float mn = mean[t];
    float s = 0.f;
    for (int b = blockIdx.x; b < K; b += gridDim.x) {
        const int idx = know[b];
        const float v = x[(size_t)idx * DD + t] - mn - oki[(size_t)b * DD + t];
        s += v * v;
    }
#pragma unroll
    for (int off = 32; off > 0; off >>= 1) s += __shfl_xor(s, off);
    if ((t & 63) == 0) red[t >> 6] = s;
    __syncthreads();
    if (t == 0) atomicAdd(&acc[2], red[0] + red[1] + red[2] + red[3]);
}

// ---------------------------------------------------------------------------
// gemm: block (mb,kc): Ypart[128,256] = L[rows,kchunk] @ xn[kchunk,:], bf16.
// Pipeline per 64-wide K-step f (2-unrolled, named reg buffers):
//   COMPUTE(f)  : pure ds_read + MFMA (no vmem)
//   s_barrier   : raw (loads stay in flight)
//   CONVERT(f+1): va regs (compiler-counted wait) -> bf16 -> swizzled LDS
//   ISSUE A(f+2) -> va, ISSUE B(f+2) -> frag regs   (land under next compute)
//   lgkmcnt(0); s_barrier
// ---------------------------------------------------------------------------
__global__ __launch_bounds__(512, 2) void gemm_kernel(const float* __restrict__ L,
                                                      const float* __restrict__ x,
                                                      const float* __restrict__ mean,
                                                      const unsigned short* __restrict__ xnG,
                                                      float* __restrict__ acc) {
    __shared__ __align__(16) unsigned short Abf0[128 * 64];  // 16KB
    __shared__ __align__(16) unsigned short Abf1[128 * 64];  // 16KB
    const int tid  = threadIdx.x;
    const int lane = tid & 63;
    const int wid  = tid >> 6;          // 0..7 : 32-col slab
    const int mb   = blockIdx.x;
    const int kc   = blockIdx.y;
    const int row0 = mb * 128;
    const int k0c  = kc * CK;

    f32x4 acc4[8][2] = {};

    // A staging: thread -> (row ar, 16-float quarter aq)
    const int ar   = tid >> 2;              // 0..127
    const int aq   = tid & 3;
    const int grow = row0 + ar;
    const unsigned swz   = (unsigned)((ar & 7) << 4);
    const unsigned abase = (unsigned)(ar * 128);
    const unsigned akb   = (unsigned)(aq * 32);
    char* A0 = (char*)Abf0;
    char* A1 = (char*)Abf1;
    float va[16];

#define ISSUE_A(f_) {                                                          \
    const int kg_ = k0c + (f_) * 64 + aq * 16;                                 \
    if (grow < NN && kg_ + 16 <= NN) {                                         \
        const f32x4* p_ = (const f32x4*)(L + (size_t)grow * NN + kg_);         \
        *(f32x4*)&va[0]  = p_[0]; *(f32x4*)&va[4]  = p_[1];                    \
        *(f32x4*)&va[8]  = p_[2]; *(f32x4*)&va[12] = p_[3];                    \
    } else {                                                                   \
        _Pragma("unroll") for (int e_ = 0; e_ < 16; ++e_)                      \
            va[e_] = (grow < NN && kg_ + e_ < NN)                              \
                   ? L[(size_t)grow * NN + kg_ + e_] : 0.f;                    \
    } }

    // 4 B-frags per wave per step, contiguous 4KB per wave: j = ni*2+kk
#define ISSUE_B(d0_, d1_, d2_, d3_, f_) {                                      \
    const unsigned short* bp_ = xnG +                                          \
        (((size_t)(kc * NSTEP + (f_)) * 32 + (size_t)wid * 4) * 64 + lane) * 8;\
    d0_ = *(const s16x8*)(bp_);        d1_ = *(const s16x8*)(bp_ + 512);       \
    d2_ = *(const s16x8*)(bp_ + 1024); d3_ = *(const s16x8*)(bp_ + 1536); }

#define CONVERT(Ad_) {                                                         \
    unsigned w_[8];                                                            \
    _Pragma("unroll") for (int e_ = 0; e_ < 8; ++e_)                           \
        w_[e_] = (unsigned)f2bf(va[2*e_]) | ((unsigned)f2bf(va[2*e_+1]) << 16);\
    *(u32x4*)((Ad_) + abase + ((akb)       ^ swz)) = *(const u32x4*)&w_[0];    \
    *(u32x4*)((Ad_) + abase + ((akb + 16u) ^ swz)) = *(const u32x4*)&w_[4]; }

#define COMPUTE(As_, b00_, b01_, b10_, b11_) {                                 \
    _Pragma("unroll") for (int kk_ = 0; kk_ < 2; ++kk_) {                      \
        _Pragma("unroll") for (int mi_ = 0; mi_ < 8; ++mi_) {                  \
            const int r_ = mi_ * 16 + (lane & 15);                             \
            const unsigned off_ = (unsigned)(r_ * 128) +                       \
                (((unsigned)(kk_ * 64 + ((lane >> 4) << 4))) ^                 \
                 ((unsigned)((r_ & 7) << 4)));                                 \
            const s16x8 af_ = *(const s16x8*)((As_) + off_);                   \
            acc4[mi_][0] = __builtin_amdgcn_mfma_f32_16x16x32_bf16(            \
                af_, (kk_ == 0 ? b00_ : b01_), acc4[mi_][0], 0, 0, 0);         \
            acc4[mi_][1] = __builtin_amdgcn_mfma_f32_16x16x32_bf16(            \
                af_, (kk_ == 0 ? b10_ : b11_), acc4[mi_][1], 0, 0, 0);         \
        } } }

    s16x8 p00, p01, p02, p03, p10, p11, p12, p13;

    // prologue
    ISSUE_A(0)
    ISSUE_B(p00, p01, p02, p03, 0)
    CONVERT(A0)                              // waits va (counted, B0 in flight)
    ISSUE_A(1)
    ISSUE_B(p10, p11, p12, p13, 1)
    asm volatile("s_waitcnt lgkmcnt(0)" ::: "memory");
    __builtin_amdgcn_s_barrier();

#pragma unroll 1
    for (int f = 0; f < NSTEP; f += 2) {
        COMPUTE(A0, p00, p01, p02, p03)      // phase f (pure LDS+MFMA)
        __builtin_amdgcn_s_barrier();        // all waves done reading A1's prev
        CONVERT(A1)                          // va = A(f+1), counted wait
        if (f + 2 < NSTEP) {
            ISSUE_A(f + 2)
            ISSUE_B(p00, p01, p02, p03, f + 2)
        }
        asm volatile("s_waitcnt lgkmcnt(0)" ::: "memory");
        __builtin_amdgcn_s_barrier();        // A1 ready
        COMPUTE(A1, p10, p11, p12, p13)      // phase f+1
        if (f + 2 < NSTEP) {
            __builtin_amdgcn_s_barrier();
            CONVERT(A0)                      // va = A(f+2)
            ISSUE_A(f + 3)
            ISSUE_B(p10, p11, p12, p13, f + 3)
            asm volatile("s_waitcnt lgkmcnt(0)" ::: "memory");
            __builtin_amdgcn_s_barrier();
        }
    }

    // ---- epilogue: partial dot with exact f32 xn; one atomic per wave ----
    float sdot = 0.f;
    const int c0 = wid * 32 + (lane & 15);
    const float mn0 = mean[c0], mn1 = mean[c0 + 16];
#pragma unroll
    for (int mi = 0; mi < 8; ++mi) {
        const int rb = row0 + mi * 16 + ((lane >> 4) << 2);
#pragma unroll
        for (int j = 0; j < 4; ++j) {
            const int r = rb + j;
            if (r < NN) {
                const float* xr = x + (size_t)r * DD + c0;
                sdot += (xr[0]  - mn0) * acc4[mi][0][j]
                      + (xr[16] - mn1) * acc4[mi][1][j];
            }
        }
    }
#pragma unroll
    for (int off = 32; off > 0; off >>= 1) sdot += __shfl_xor(sdot, off);
    if (lane == 0) atomicAdd(&acc[0], sdot);
#undef ISSUE_A
#undef ISSUE_B
#undef CONVERT
#undef COMPUTE
}

// ---------------------------------------------------------------------------
// finalize: out = -(dir + eta*recon + theta*(n/(n-1)*ss - colsq/(n-1)))
// ---------------------------------------------------------------------------
__global__ __launch_bounds__(256) void fin_kernel(const float* __restrict__ acc,
                                                  const float* __restrict__ theta,
                                                  const float* __restrict__ eta,
                                                  float* __restrict__ out) {
    __shared__ float red[4];
    const int t = threadIdx.x;
    const float c = acc[4 + t];
    float s = c * c;
#pragma unroll
    for (int off = 32; off > 0; off >>= 1) s += __shfl_xor(s, off);
    if ((t & 63) == 0) red[t >> 6] = s;
    __syncthreads();
    if (t == 0) {
        const float colsq = red[0] + red[1] + red[2] + red[3];
        const float n = (float)NN;
        const float avg = (n / (n - 1.f)) * acc[1] - colsq / (n - 1.f);
        out[0] = -(acc[0] + eta[0] * acc[2] + theta[0] * avg);
    }
}

extern "C" void kernel_launch(void* const* d_in, const int* in_sizes, int n_in,
                              void* d_out, int out_size, void* d_ws, size_t ws_size,
                              hipStream_t stream) {
    const float* x     = (const float*)d_in[0];
    const float* L     = (const float*)d_in[1];
    const float* mean  = (const float*)d_in[2];
    const float* oki   = (const float*)d_in[3];
    const int*   know  = (const int*)d_in[4];
    const float* theta = (const float*)d_in[5];
    const float* eta   = (const float*)d_in[6];
    float* out = (float*)d_out;

    unsigned short* xnG = (unsigned short*)d_ws;
    float* acc = (float*)((char*)d_ws + (size_t)NKB * 2048 * 16);  // 5.24MB
    const int K = in_sizes[4];

    hipMemsetAsync(acc, 0, 260 * sizeof(float), stream);
    hipLaunchKernelGGL(prep_kernel,  dim3(NKB),      dim3(256), 0, stream, x, mean, xnG, acc);
    hipLaunchKernelGGL(recon_kernel, dim3(256),      dim3(256), 0, stream, x, mean, oki, know, K, acc);
    hipLaunchKernelGGL(gemm_kernel,  dim3(NMB, NKC), dim3(512), 0, stream, L, x, mean, xnG, acc);
    hipLaunchKernelGGL(fin_kernel,   dim3(1),        dim3(256), 0, stream, acc, theta, eta, out);
}

// Round 4
// 224.953 us; speedup vs baseline: 1.3308x; 1.1987x over previous
//
#include <hip/hip_runtime.h>

// arbLoss: -(dirichlet + eta*recon + theta*avg)
//   dirichlet = <L, G> with G = xn @ xn^T  (both symmetric!)
//             = sum_diag_blocks(L.G) + 2*sum_{bi<bk}(L.G)
//   avg       = n/(n-1)*sum(xn^2) - 1/(n-1)*sum(colsum^2)
//   recon     = sum((xn[know]-out_k_init)^2)
// inputs: 0:x[N,D] f32  1:L[N,N] f32  2:mean[D] f32  3:out_k_init[K,D] f32
//         4:know_mask[K] int  5:theta f32  6:eta f32     out: scalar f32
//
// R4 design: Gram reformulation. MFMA inputs = xn only (5MB, cache-resident);
// L is a pure register-streamed reduction operand (no LDS, no barriers, waves
// fully desynced). Upper-triangular block enumeration halves L traffic & FLOPs.

#define NN    10000
#define DD    256
#define NB    79      // 128-wide blocks: 79*128 = 10112
#define NPAIR 3160    // NB*(NB+1)/2 upper-tri block pairs
#define NR16  632     // 16-row blocks (10112/16)
#define PREPB 158     // 10112/64

typedef float  f32x4 __attribute__((ext_vector_type(4)));
typedef short  s16x8 __attribute__((ext_vector_type(8)));

__device__ __forceinline__ unsigned short f2bf(float f) {
    union { float f; unsigned u; } c; c.f = f;
    unsigned u = c.u;
    u += 0x7fffu + ((u >> 16) & 1u);   // round-to-nearest-even
    return (unsigned short)(u >> 16);
}

// ---------------------------------------------------------------------------
// prep: xnF = bf16 xn in MFMA A/B-operand fragment layout, 16-row granularity:
//   frag (r16, fb) at xnF[((r16*8+fb)*64+lane)*8 + j]
//     = xn[r16*16 + (lane&15)][fb*32 + (lane>>4)*8 + j]
// (identical layout serves A- and B-operands of G = xn @ xn^T.)
// rows >= NN zero-padded. Also colsum -> acc[4+f], sum(xn^2) -> acc[1].
// acc layout (f32): [0]=dirichlet [1]=ss [2]=recon [3]=pad [4..259]=colsum
// ---------------------------------------------------------------------------
__global__ __launch_bounds__(256) void prep_kernel(const float* __restrict__ x,
                                                   const float* __restrict__ mean,
                                                   unsigned short* __restrict__ xnF,
                                                   float* __restrict__ acc) {
    __shared__ __align__(16) unsigned short xs[64][264];  // 528B row stride (16B-aligned)
    __shared__ float red[4];
    const int t  = threadIdx.x;              // 0..255 == column f
    const int i0 = blockIdx.x * 64;
    const float mn = mean[t];
    float css = 0.f, ss = 0.f;
    for (int ii = 0; ii < 64; ++ii) {
        const int i = i0 + ii;
        float v = 0.f;
        if (i < NN) v = x[(size_t)i * DD + t] - mn;
        css += v; ss += v * v;
        xs[ii][t] = f2bf(v);
    }
    atomicAdd(&acc[4 + t], css);
#pragma unroll
    for (int off = 32; off > 0; off >>= 1) ss += __shfl_xor(ss, off);
    if ((t & 63) == 0) red[t >> 6] = ss;
    __syncthreads();                         // xs + red ready
    if (t == 0) atomicAdd(&acc[1], red[0] + red[1] + red[2] + red[3]);
    const int lane = t & 63;
    const int q    = t >> 6;
#pragma unroll
    for (int p = 0; p < 8; ++p) {
        const int fq   = p * 4 + q;          // frag slot 0..31
        const int r16l = fq >> 3;            // 0..3
        const int fb   = fq & 7;             // 0..7
        const s16x8 v = *(const s16x8*)&xs[r16l * 16 + (lane & 15)]
                                          [fb * 32 + ((lane >> 4) << 3)];
        const size_t rg16 = (size_t)blockIdx.x * 4 + r16l;
        *(s16x8*)(xnF + ((rg16 * 8 + fb) * 64 + lane) * 8) = v;
    }
}

// ---------------------------------------------------------------------------
// recon: sum((x[know]-mean - out_k_init)^2)
// ---------------------------------------------------------------------------
__global__ __launch_bounds__(256) void recon_kernel(const float* __restrict__ x,
                                                    const float* __restrict__ mean,
                                                    const float* __restrict__ oki,
                                                    const int* __restrict__ know,
                                                    int K, float* __restrict__ acc) {
    __shared__ float red[4];
    const int t = threadIdx.x;
    const float mn = mean[t];
    float s = 0.f;
    for (int b = blockIdx.x; b < K; b += gridDim.x) {
        const int idx = know[b];
        const float v = x[(size_t)idx * DD + t] - mn - oki[(size_t)b * DD + t];
        s += v * v;
    }
#pragma unroll
    for (int off = 32; off > 0; off >>= 1) s += __shfl_xor(s, off);
    if ((t & 63) == 0) red[t >> 6] = s;
    __syncthreads();
    if (t == 0) atomicAdd(&acc[2], red[0] + red[1] + red[2] + red[3]);
}

// ---------------------------------------------------------------------------
// gram: block = upper-tri 128x128 tile pair (bi,bk). 4 waves in 2x2, each owns
// a 64x64 G sub-tile: G = xn_I @ xn_K^T via 128 MFMA from cache-hot xnF frags.
// Then stream L tile into 64 regs/thread (HBM), sdot = sum(L .* G), factor 2
// for off-diagonal blocks. No LDS, no barriers.
// ---------------------------------------------------------------------------
__global__ __launch_bounds__(256, 2) void gram_kernel(const float* __restrict__ L,
                                                      const unsigned short* __restrict__ xnF,
                                                      float* __restrict__ acc) {
    const int tid  = threadIdx.x;
    const int lane = tid & 63;
    const int wid  = tid >> 6;
    const int wr   = wid >> 1, wc = wid & 1;
    const int t    = blockIdx.x;
    // triangular decode: bi = largest r with off(r) <= t, off(r) = r*NB - r(r-1)/2
    int bi = (int)(((float)(2 * NB + 1) -
                    sqrtf((float)((2 * NB + 1) * (2 * NB + 1) - 8 * t))) * 0.5f);
    if (bi < 0) bi = 0;
    if (bi > NB - 1) bi = NB - 1;
    while (bi > 0 && bi * NB - bi * (bi - 1) / 2 > t) --bi;
    while ((bi + 1) * NB - (bi + 1) * bi / 2 <= t) ++bi;
    const int bk = bi + (t - (bi * NB - bi * (bi - 1) / 2));

    const int row0 = bi * 128 + wr * 64;
    const int col0 = bk * 128 + wc * 64;
    const int ra = row0 >> 4;            // 16-row frag base, A side
    const int rb = col0 >> 4;            // 16-row frag base, B side

    f32x4 g[4][4] = {};                  // [mi][ni], 16x16 each
#pragma unroll
    for (int fb = 0; fb < 8; ++fb) {
        s16x8 af[4], bfr[4];
#pragma unroll
        for (int mi = 0; mi < 4; ++mi)
            af[mi] = *(const s16x8*)(xnF + (((size_t)(ra + mi) * 8 + fb) * 64 + lane) * 8);
#pragma unroll
        for (int ni = 0; ni < 4; ++ni)
            bfr[ni] = *(const s16x8*)(xnF + (((size_t)(rb + ni) * 8 + fb) * 64 + lane) * 8);
#pragma unroll
        for (int mi = 0; mi < 4; ++mi)
#pragma unroll
            for (int ni = 0; ni < 4; ++ni)
                g[mi][ni] = __builtin_amdgcn_mfma_f32_16x16x32_bf16(
                    af[mi], bfr[ni], g[mi][ni], 0, 0, 0);
    }

    // L tile: C/D layout row = mi*16 + (lane>>4)*4 + j, col = ni*16 + (lane&15)
    float lv[4][4][4];                   // [mi][j][ni] — 64 regs, static idx
    const int cbase = col0 + (lane & 15);
    const int rj    = (lane >> 4) << 2;
#pragma unroll
    for (int mi = 0; mi < 4; ++mi)
#pragma unroll
        for (int j = 0; j < 4; ++j) {
            const int r = row0 + mi * 16 + rj + j;
            const bool rok = (r < NN);
            const float* Lr = L + (size_t)r * NN + cbase;
#pragma unroll
            for (int ni = 0; ni < 4; ++ni)
                lv[mi][j][ni] = (rok && (cbase + ni * 16) < NN) ? Lr[ni * 16] : 0.f;
        }

    float sdot = 0.f;
#pragma unroll
    for (int mi = 0; mi < 4; ++mi)
#pragma unroll
        for (int j = 0; j < 4; ++j)
#pragma unroll
            for (int ni = 0; ni < 4; ++ni)
                sdot += lv[mi][j][ni] * g[mi][ni][j];

#pragma unroll
    for (int off = 32; off > 0; off >>= 1) sdot += __shfl_xor(sdot, off);
    if (lane == 0) {
        const float fac = (bi == bk) ? 1.f : 2.f;
        atomicAdd(&acc[0], fac * sdot);
    }
}

// ---------------------------------------------------------------------------
// finalize: out = -(dir + eta*recon + theta*(n/(n-1)*ss - colsq/(n-1)))
// ---------------------------------------------------------------------------
__global__ __launch_bounds__(256) void fin_kernel(const float* __restrict__ acc,
                                                  const float* __restrict__ theta,
                                                  const float* __restrict__ eta,
                                                  float* __restrict__ out) {
    __shared__ float red[4];
    const int t = threadIdx.x;
    const float c = acc[4 + t];
    float s = c * c;
#pragma unroll
    for (int off = 32; off > 0; off >>= 1) s += __shfl_xor(s, off);
    if ((t & 63) == 0) red[t >> 6] = s;
    __syncthreads();
    if (t == 0) {
        const float colsq = red[0] + red[1] + red[2] + red[3];
        const float n = (float)NN;
        const float avg = (n / (n - 1.f)) * acc[1] - colsq / (n - 1.f);
        out[0] = -(acc[0] + eta[0] * acc[2] + theta[0] * avg);
    }
}

extern "C" void kernel_launch(void* const* d_in, const int* in_sizes, int n_in,
                              void* d_out, int out_size, void* d_ws, size_t ws_size,
                              hipStream_t stream) {
    const float* x     = (const float*)d_in[0];
    const float* L     = (const float*)d_in[1];
    const float* mean  = (const float*)d_in[2];
    const float* oki   = (const float*)d_in[3];
    const int*   know  = (const int*)d_in[4];
    const float* theta = (const float*)d_in[5];
    const float* eta   = (const float*)d_in[6];
    float* out = (float*)d_out;

    unsigned short* xnF = (unsigned short*)d_ws;
    float* acc = (float*)((char*)d_ws + (size_t)NR16 * 8 * 64 * 16);  // 5.18MB
    const int K = in_sizes[4];

    hipMemsetAsync(acc, 0, 260 * sizeof(float), stream);
    hipLaunchKernelGGL(prep_kernel,  dim3(PREPB), dim3(256), 0, stream, x, mean, xnF, acc);
    hipLaunchKernelGGL(recon_kernel, dim3(256),   dim3(256), 0, stream, x, mean, oki, know, K, acc);
    hipLaunchKernelGGL(gram_kernel,  dim3(NPAIR), dim3(256), 0, stream, L, xnF, acc);
    hipLaunchKernelGGL(fin_kernel,   dim3(1),     dim3(256), 0, stream, acc, theta, eta, out);
}

// Round 5
// 123.496 us; speedup vs baseline: 2.4241x; 1.8215x over previous
//
#include <hip/hip_runtime.h>

// arbLoss: -(dirichlet + eta*recon + theta*avg)
//   dirichlet = <L, G> with G = xn @ xn^T  (both symmetric!)
//             = sum_diag_blocks(L.G) + 2*sum_{bi<bk}(L.G)
//   avg       = n/(n-1)*sum(xn^2) - 1/(n-1)*sum(colsum^2)
//   recon     = sum((xn[know]-out_k_init)^2)
// inputs: 0:x[N,D] f32  1:L[N,N] f32  2:mean[D] f32  3:out_k_init[K,D] f32
//         4:know_mask[K] int  5:theta f32  6:eta f32     out: scalar f32
//
// R5: R4's Gram structure, but ZERO same-address atomics (R1-R4 were bound by
// ~12K serialized atomicAdds to acc[0] at ~20ns each). All partials go to
// dense per-block buffers; fin_kernel reduces them.

#define NN    10000
#define DD    256
#define NB    79      // 128-wide blocks: 79*128 = 10112
#define NPAIR 3160    // NB*(NB+1)/2 upper-tri block pairs
#define NR16  632     // 16-row blocks (10112/16)
#define PREPB 158     // 10112/64

typedef float  f32x4 __attribute__((ext_vector_type(4)));
typedef short  s16x8 __attribute__((ext_vector_type(8)));

__device__ __forceinline__ unsigned short f2bf(float f) {
    union { float f; unsigned u; } c; c.f = f;
    unsigned u = c.u;
    u += 0x7fffu + ((u >> 16) & 1u);   // round-to-nearest-even
    return (unsigned short)(u >> 16);
}

// ---------------------------------------------------------------------------
// prep: xnF = bf16 xn in MFMA A/B-operand fragment layout, 16-row granularity:
//   frag (r16, fb) at xnF[((r16*8+fb)*64+lane)*8 + j]
//     = xn[r16*16 + (lane&15)][fb*32 + (lane>>4)*8 + j]
// rows >= NN zero-padded. Partials: csbuf[blk][256] colsums, ssbuf[blk] sum(xn^2).
// ---------------------------------------------------------------------------
__global__ __launch_bounds__(256) void prep_kernel(const float* __restrict__ x,
                                                   const float* __restrict__ mean,
                                                   unsigned short* __restrict__ xnF,
                                                   float* __restrict__ csbuf,
                                                   float* __restrict__ ssbuf) {
    __shared__ __align__(16) unsigned short xs[64][264];
    __shared__ float red[4];
    const int t  = threadIdx.x;              // 0..255 == column f
    const int i0 = blockIdx.x * 64;
    const float mn = mean[t];
    float css = 0.f, ss = 0.f;
    for (int ii = 0; ii < 64; ++ii) {
        const int i = i0 + ii;
        float v = 0.f;
        if (i < NN) v = x[(size_t)i * DD + t] - mn;
        css += v; ss += v * v;
        xs[ii][t] = f2bf(v);
    }
    csbuf[(size_t)blockIdx.x * 256 + t] = css;
#pragma unroll
    for (int off = 32; off > 0; off >>= 1) ss += __shfl_xor(ss, off);
    if ((t & 63) == 0) red[t >> 6] = ss;
    __syncthreads();                         // xs + red ready
    if (t == 0) ssbuf[blockIdx.x] = red[0] + red[1] + red[2] + red[3];
    const int lane = t & 63;
    const int q    = t >> 6;
#pragma unroll
    for (int p = 0; p < 8; ++p) {
        const int fq   = p * 4 + q;          // frag slot 0..31
        const int r16l = fq >> 3;            // 0..3
        const int fb   = fq & 7;             // 0..7
        const s16x8 v = *(const s16x8*)&xs[r16l * 16 + (lane & 15)]
                                          [fb * 32 + ((lane >> 4) << 3)];
        const size_t rg16 = (size_t)blockIdx.x * 4 + r16l;
        *(s16x8*)(xnF + ((rg16 * 8 + fb) * 64 + lane) * 8) = v;
    }
}

// ---------------------------------------------------------------------------
// recon: per-block partial of sum((x[know]-mean - out_k_init)^2) -> rbuf[blk]
// ---------------------------------------------------------------------------
__global__ __launch_bounds__(256) void recon_kernel(const float* __restrict__ x,
                                                    const float* __restrict__ mean,
                                                    const float* __restrict__ oki,
                                                    const int* __restrict__ know,
                                                    int K, float* __restrict__ rbuf) {
    __shared__ float red[4];
    const int t = threadIdx.x;
    const float mn = mean[t];
    float s = 0.f;
    for (int b = blockIdx.x; b < K; b += gridDim.x) {
        const int idx = know[b];
        const float v = x[(size_t)idx * DD + t] - mn - oki[(size_t)b * DD + t];
        s += v * v;
    }
#pragma unroll
    for (int off = 32; off > 0; off >>= 1) s += __shfl_xor(s, off);
    if ((t & 63) == 0) red[t >> 6] = s;
    __syncthreads();
    if (t == 0) rbuf[blockIdx.x] = red[0] + red[1] + red[2] + red[3];
}

// ---------------------------------------------------------------------------
// gram: block = upper-tri 128x128 tile pair (bi,bk). 4 waves in 2x2, each owns
// a 64x64 G sub-tile: G = xn_I @ xn_K^T via 128 MFMA from cache-hot xnF frags.
// Then stream L tile into 64 regs/thread (HBM), sdot = sum(L .* G), factor 2
// for off-diagonal blocks. No LDS tiles, no barriers in the hot path, and ONE
// plain store per block (no atomics).
// ---------------------------------------------------------------------------
__global__ __launch_bounds__(256, 2) void gram_kernel(const float* __restrict__ L,
                                                      const unsigned short* __restrict__ xnF,
                                                      float* __restrict__ part) {
    const int tid  = threadIdx.x;
    const int lane = tid & 63;
    const int wid  = tid >> 6;
    const int wr   = wid >> 1, wc = wid & 1;
    const int t    = blockIdx.x;
    // triangular decode: bi = largest r with off(r) <= t, off(r) = r*NB - r(r-1)/2
    int bi = (int)(((float)(2 * NB + 1) -
                    sqrtf((float)((2 * NB + 1) * (2 * NB + 1) - 8 * t))) * 0.5f);
    if (bi < 0) bi = 0;
    if (bi > NB - 1) bi = NB - 1;
    while (bi > 0 && bi * NB - bi * (bi - 1) / 2 > t) --bi;
    while ((bi + 1) * NB - (bi + 1) * bi / 2 <= t) ++bi;
    const int bk = bi + (t - (bi * NB - bi * (bi - 1) / 2));

    const int row0 = bi * 128 + wr * 64;
    const int col0 = bk * 128 + wc * 64;
    const int ra = row0 >> 4;            // 16-row frag base, A side
    const int rb = col0 >> 4;            // 16-row frag base, B side

    f32x4 g[4][4] = {};                  // [mi][ni], 16x16 each
#pragma unroll
    for (int fb = 0; fb < 8; ++fb) {
        s16x8 af[4], bfr[4];
#pragma unroll
        for (int mi = 0; mi < 4; ++mi)
            af[mi] = *(const s16x8*)(xnF + (((size_t)(ra + mi) * 8 + fb) * 64 + lane) * 8);
#pragma unroll
        for (int ni = 0; ni < 4; ++ni)
            bfr[ni] = *(const s16x8*)(xnF + (((size_t)(rb + ni) * 8 + fb) * 64 + lane) * 8);
#pragma unroll
        for (int mi = 0; mi < 4; ++mi)
#pragma unroll
            for (int ni = 0; ni < 4; ++ni)
                g[mi][ni] = __builtin_amdgcn_mfma_f32_16x16x32_bf16(
                    af[mi], bfr[ni], g[mi][ni], 0, 0, 0);
    }

    // L tile: C/D layout row = mi*16 + (lane>>4)*4 + j, col = ni*16 + (lane&15)
    float lv[4][4][4];                   // [mi][j][ni] — 64 regs, static idx
    const int cbase = col0 + (lane & 15);
    const int rj    = (lane >> 4) << 2;
#pragma unroll
    for (int mi = 0; mi < 4; ++mi)
#pragma unroll
        for (int j = 0; j < 4; ++j) {
            const int r = row0 + mi * 16 + rj + j;
            const bool rok = (r < NN);
            const float* Lr = L + (size_t)r * NN + cbase;
#pragma unroll
            for (int ni = 0; ni < 4; ++ni)
                lv[mi][j][ni] = (rok && (cbase + ni * 16) < NN) ? Lr[ni * 16] : 0.f;
        }

    float sdot = 0.f;
#pragma unroll
    for (int mi = 0; mi < 4; ++mi)
#pragma unroll
        for (int j = 0; j < 4; ++j)
#pragma unroll
            for (int ni = 0; ni < 4; ++ni)
                sdot += lv[mi][j][ni] * g[mi][ni][j];

#pragma unroll
    for (int off = 32; off > 0; off >>= 1) sdot += __shfl_xor(sdot, off);
    __shared__ float wred[4];
    if (lane == 0) wred[wid] = sdot;
    __syncthreads();
    if (tid == 0) {
        const float fac = (bi == bk) ? 1.f : 2.f;
        part[t] = fac * (wred[0] + wred[1] + wred[2] + wred[3]);
    }
}

// ---------------------------------------------------------------------------
// fin: reduce part[NPAIR], csbuf[PREPB][256], ssbuf[PREPB], rbuf[256]:
//   out = -(dir + eta*recon + theta*(n/(n-1)*ss - colsq/(n-1)))
// ---------------------------------------------------------------------------
__global__ __launch_bounds__(256) void fin_kernel(const float* __restrict__ part,
                                                  const float* __restrict__ csbuf,
                                                  const float* __restrict__ ssbuf,
                                                  const float* __restrict__ rbuf,
                                                  const float* __restrict__ theta,
                                                  const float* __restrict__ eta,
                                                  float* __restrict__ out) {
    __shared__ float red[4][4];
    const int t = threadIdx.x;
    float sp = 0.f;
    for (int i = t; i < NPAIR; i += 256) sp += part[i];
    float cs = 0.f;
    for (int b = 0; b < PREPB; ++b) cs += csbuf[(size_t)b * 256 + t];
    float c2 = cs * cs;
    float ssv = (t < PREPB) ? ssbuf[t] : 0.f;
    float rv  = rbuf[t];
#pragma unroll
    for (int off = 32; off > 0; off >>= 1) {
        sp  += __shfl_xor(sp, off);
        c2  += __shfl_xor(c2, off);
        ssv += __shfl_xor(ssv, off);
        rv  += __shfl_xor(rv, off);
    }
    if ((t & 63) == 0) {
        red[t >> 6][0] = sp; red[t >> 6][1] = c2;
        red[t >> 6][2] = ssv; red[t >> 6][3] = rv;
    }
    __syncthreads();
    if (t == 0) {
        float dir = 0.f, colsq = 0.f, ss = 0.f, rec = 0.f;
#pragma unroll
        for (int w = 0; w < 4; ++w) {
            dir += red[w][0]; colsq += red[w][1];
            ss  += red[w][2]; rec   += red[w][3];
        }
        const float n = (float)NN;
        const float avg = (n / (n - 1.f)) * ss - colsq / (n - 1.f);
        out[0] = -(dir + eta[0] * rec + theta[0] * avg);
    }
}

extern "C" void kernel_launch(void* const* d_in, const int* in_sizes, int n_in,
                              void* d_out, int out_size, void* d_ws, size_t ws_size,
                              hipStream_t stream) {
    const float* x     = (const float*)d_in[0];
    const float* L     = (const float*)d_in[1];
    const float* mean  = (const float*)d_in[2];
    const float* oki   = (const float*)d_in[3];
    const int*   know  = (const int*)d_in[4];
    const float* theta = (const float*)d_in[5];
    const float* eta   = (const float*)d_in[6];
    float* out = (float*)d_out;

    char* ws = (char*)d_ws;
    unsigned short* xnF = (unsigned short*)ws;                 // 5,177,344 B
    float* part  = (float*)(ws + 6 * 1024 * 1024);             // NPAIR f32
    float* csbuf = (float*)(ws + 7 * 1024 * 1024);             // PREPB*256 f32
    float* ssbuf = (float*)(ws + 8 * 1024 * 1024);             // PREPB f32
    float* rbuf  = (float*)(ws + 8 * 1024 * 1024 + 4096);      // 256 f32
    const int K = in_sizes[4];

    hipLaunchKernelGGL(prep_kernel,  dim3(PREPB), dim3(256), 0, stream, x, mean, xnF, csbuf, ssbuf);
    hipLaunchKernelGGL(recon_kernel, dim3(256),   dim3(256), 0, stream, x, mean, oki, know, K, rbuf);
    hipLaunchKernelGGL(gram_kernel,  dim3(NPAIR), dim3(256), 0, stream, L, xnF, part);
    hipLaunchKernelGGL(fin_kernel,   dim3(1),     dim3(256), 0, stream, part, csbuf, ssbuf, rbuf, theta, eta, out);
}

// Round 6
// 121.995 us; speedup vs baseline: 2.4539x; 1.0123x over previous
//
#include <hip/hip_runtime.h>

// arbLoss: -(dirichlet + eta*recon + theta*avg)
//   dirichlet = <L, G> with G = xn @ xn^T  (both symmetric!)
//             = sum_diag_blocks(L.G) + 2*sum_{bi<bk}(L.G)
//   avg       = n/(n-1)*sum(xn^2) - 1/(n-1)*sum(colsum^2)
//   recon     = sum((xn[know]-out_k_init)^2)
// inputs: 0:x[N,D] f32  1:L[N,N] f32  2:mean[D] f32  3:out_k_init[K,D] f32
//         4:know_mask[K] int  5:theta f32  6:eta f32     out: scalar f32
//
// R6: R5 (Gram + no same-address atomics) with gram restructured for
// HBM/MFMA overlap: L-row chunks issued INSIDE the fb MFMA loop (pinned by
// sched_barrier), frag loads double-buffered 1 ahead. HBM streams during the
// whole MFMA phase instead of starting after it.

#define NN    10000
#define DD    256
#define NB    79      // 128-wide blocks: 79*128 = 10112
#define NPAIR 3160    // NB*(NB+1)/2 upper-tri block pairs
#define NR16  632     // 16-row blocks (10112/16)
#define PREPB 158     // 10112/64

typedef float  f32x4 __attribute__((ext_vector_type(4)));
typedef short  s16x8 __attribute__((ext_vector_type(8)));

__device__ __forceinline__ unsigned short f2bf(float f) {
    union { float f; unsigned u; } c; c.f = f;
    unsigned u = c.u;
    u += 0x7fffu + ((u >> 16) & 1u);   // round-to-nearest-even
    return (unsigned short)(u >> 16);
}

// ---------------------------------------------------------------------------
// prep: xnF = bf16 xn in MFMA A/B-operand fragment layout, 16-row granularity:
//   frag (r16, fb) at xnF[((r16*8+fb)*64+lane)*8 + j]
//     = xn[r16*16 + (lane&15)][fb*32 + (lane>>4)*8 + j]
// rows >= NN zero-padded. Partials: csbuf[blk][256] colsums, ssbuf[blk] sum(xn^2).
// ---------------------------------------------------------------------------
__global__ __launch_bounds__(256) void prep_kernel(const float* __restrict__ x,
                                                   const float* __restrict__ mean,
                                                   unsigned short* __restrict__ xnF,
                                                   float* __restrict__ csbuf,
                                                   float* __restrict__ ssbuf) {
    __shared__ __align__(16) unsigned short xs[64][264];
    __shared__ float red[4];
    const int t  = threadIdx.x;              // 0..255 == column f
    const int i0 = blockIdx.x * 64;
    const float mn = mean[t];
    float css = 0.f, ss = 0.f;
    for (int ii = 0; ii < 64; ++ii) {
        const int i = i0 + ii;
        float v = 0.f;
        if (i < NN) v = x[(size_t)i * DD + t] - mn;
        css += v; ss += v * v;
        xs[ii][t] = f2bf(v);
    }
    csbuf[(size_t)blockIdx.x * 256 + t] = css;
#pragma unroll
    for (int off = 32; off > 0; off >>= 1) ss += __shfl_xor(ss, off);
    if ((t & 63) == 0) red[t >> 6] = ss;
    __syncthreads();                         // xs + red ready
    if (t == 0) ssbuf[blockIdx.x] = red[0] + red[1] + red[2] + red[3];
    const int lane = t & 63;
    const int q    = t >> 6;
#pragma unroll
    for (int p = 0; p < 8; ++p) {
        const int fq   = p * 4 + q;          // frag slot 0..31
        const int r16l = fq >> 3;            // 0..3
        const int fb   = fq & 7;             // 0..7
        const s16x8 v = *(const s16x8*)&xs[r16l * 16 + (lane & 15)]
                                          [fb * 32 + ((lane >> 4) << 3)];
        const size_t rg16 = (size_t)blockIdx.x * 4 + r16l;
        *(s16x8*)(xnF + ((rg16 * 8 + fb) * 64 + lane) * 8) = v;
    }
}

// ---------------------------------------------------------------------------
// recon: per-block partial of sum((x[know]-mean - out_k_init)^2) -> rbuf[blk]
// ---------------------------------------------------------------------------
__global__ __launch_bounds__(256) void recon_kernel(const float* __restrict__ x,
                                                    const float* __restrict__ mean,
                                                    const float* __restrict__ oki,
                                                    const int* __restrict__ know,
                                                    int K, float* __restrict__ rbuf) {
    __shared__ float red[4];
    const int t = threadIdx.x;
    const float mn = mean[t];
    float s = 0.f;
    for (int b = blockIdx.x; b < K; b += gridDim.x) {
        const int idx = know[b];
        const float v = x[(size_t)idx * DD + t] - mn - oki[(size_t)b * DD + t];
        s += v * v;
    }
#pragma unroll
    for (int off = 32; off > 0; off >>= 1) s += __shfl_xor(s, off);
    if ((t & 63) == 0) red[t >> 6] = s;
    __syncthreads();
    if (t == 0) rbuf[blockIdx.x] = red[0] + red[1] + red[2] + red[3];
}

// ---------------------------------------------------------------------------
// gram: block = upper-tri 128x128 tile pair (bi,bk). 4 waves in 2x2, each owns
// a 64x64 G sub-tile: G = xn_I @ xn_K^T via 128 MFMA from cache-hot xnF frags.
// L-row chunks (2 of 16 per fb iteration) are issued inside the MFMA loop so
// HBM streams under compute; frag loads double-buffered one fb ahead.
// One plain store per block; no atomics, no LDS tiles in the hot path.
// ---------------------------------------------------------------------------
__global__ __launch_bounds__(256, 2) void gram_kernel(const float* __restrict__ L,
                                                      const unsigned short* __restrict__ xnF,
                                                      float* __restrict__ part) {
    const int tid  = threadIdx.x;
    const int lane = tid & 63;
    const int wid  = tid >> 6;
    const int wr   = wid >> 1, wc = wid & 1;
    const int t    = blockIdx.x;
    // triangular decode: bi = largest r with off(r) <= t, off(r) = r*NB - r(r-1)/2
    int bi = (int)(((float)(2 * NB + 1) -
                    sqrtf((float)((2 * NB + 1) * (2 * NB + 1) - 8 * t))) * 0.5f);
    if (bi < 0) bi = 0;
    if (bi > NB - 1) bi = NB - 1;
    while (bi > 0 && bi * NB - bi * (bi - 1) / 2 > t) --bi;
    while ((bi + 1) * NB - (bi + 1) * bi / 2 <= t) ++bi;
    const int bk = bi + (t - (bi * NB - bi * (bi - 1) / 2));

    const int row0 = bi * 128 + wr * 64;
    const int col0 = bk * 128 + wc * 64;
    const int ra = row0 >> 4;            // 16-row frag base, A side
    const int rb = col0 >> 4;            // 16-row frag base, B side

    const int cbase = col0 + (lane & 15);
    const int rj    = (lane >> 4) << 2;

    f32x4 g[4][4] = {};                  // [mi][ni], 16x16 each
    float lv[4][4][4];                   // [mi][j][ni] — static idx only
    s16x8 af[2][4], bfr[2][4];           // double-buffered frags

#define FRAGLOAD(buf_, fb_) {                                                  \
    _Pragma("unroll") for (int mi_ = 0; mi_ < 4; ++mi_)                        \
        af[buf_][mi_] = *(const s16x8*)(xnF +                                  \
            (((size_t)(ra + mi_) * 8 + (fb_)) * 64 + lane) * 8);               \
    _Pragma("unroll") for (int ni_ = 0; ni_ < 4; ++ni_)                        \
        bfr[buf_][ni_] = *(const s16x8*)(xnF +                                 \
            (((size_t)(rb + ni_) * 8 + (fb_)) * 64 + lane) * 8); }

    // L chunk p (0..15): mi = p>>2, j = p&3 -> 4 scalar loads (one 16-col row)
#define LCHUNK(p_) {                                                           \
    const int mi_ = (p_) >> 2, j_ = (p_) & 3;                                  \
    const int r_  = row0 + mi_ * 16 + rj + j_;                                 \
    const bool rok_ = (r_ < NN);                                               \
    const float* Lr_ = L + (size_t)r_ * NN + cbase;                            \
    _Pragma("unroll") for (int ni_ = 0; ni_ < 4; ++ni_)                        \
        lv[mi_][j_][ni_] = (rok_ && cbase + ni_ * 16 < NN)                     \
                         ? Lr_[ni_ * 16] : 0.f; }

    FRAGLOAD(0, 0)
#pragma unroll
    for (int fb = 0; fb < 8; ++fb) {
        const int cur = fb & 1;
        if (fb < 7) FRAGLOAD(cur ^ 1, fb + 1)
        LCHUNK(fb * 2)
        LCHUNK(fb * 2 + 1)
        __builtin_amdgcn_sched_barrier(0);   // pin loads before this MFMA set
#pragma unroll
        for (int mi = 0; mi < 4; ++mi)
#pragma unroll
            for (int ni = 0; ni < 4; ++ni)
                g[mi][ni] = __builtin_amdgcn_mfma_f32_16x16x32_bf16(
                    af[cur][mi], bfr[cur][ni], g[mi][ni], 0, 0, 0);
        __builtin_amdgcn_sched_barrier(0);
    }
#undef FRAGLOAD
#undef LCHUNK

    float sdot = 0.f;
#pragma unroll
    for (int mi = 0; mi < 4; ++mi)
#pragma unroll
        for (int j = 0; j < 4; ++j)
#pragma unroll
            for (int ni = 0; ni < 4; ++ni)
                sdot += lv[mi][j][ni] * g[mi][ni][j];

#pragma unroll
    for (int off = 32; off > 0; off >>= 1) sdot += __shfl_xor(sdot, off);
    __shared__ float wred[4];
    if (lane == 0) wred[wid] = sdot;
    __syncthreads();
    if (tid == 0) {
        const float fac = (bi == bk) ? 1.f : 2.f;
        part[t] = fac * (wred[0] + wred[1] + wred[2] + wred[3]);
    }
}

// ---------------------------------------------------------------------------
// fin: reduce part[NPAIR], csbuf[PREPB][256], ssbuf[PREPB], rbuf[256]:
//   out = -(dir + eta*recon + theta*(n/(n-1)*ss - colsq/(n-1)))
// ---------------------------------------------------------------------------
__global__ __launch_bounds__(256) void fin_kernel(const float* __restrict__ part,
                                                  const float* __restrict__ csbuf,
                                                  const float* __restrict__ ssbuf,
                                                  const float* __restrict__ rbuf,
                                                  const float* __restrict__ theta,
                                                  const float* __restrict__ eta,
                                                  float* __restrict__ out) {
    __shared__ float red[4][4];
    const int t = threadIdx.x;
    float sp = 0.f;
    for (int i = t; i < NPAIR; i += 256) sp += part[i];
    float cs = 0.f;
    for (int b = 0; b < PREPB; ++b) cs += csbuf[(size_t)b * 256 + t];
    float c2 = cs * cs;
    float ssv = (t < PREPB) ? ssbuf[t] : 0.f;
    float rv  = rbuf[t];
#pragma unroll
    for (int off = 32; off > 0; off >>= 1) {
        sp  += __shfl_xor(sp, off);
        c2  += __shfl_xor(c2, off);
        ssv += __shfl_xor(ssv, off);
        rv  += __shfl_xor(rv, off);
    }
    if ((t & 63) == 0) {
        red[t >> 6][0] = sp; red[t >> 6][1] = c2;
        red[t >> 6][2] = ssv; red[t >> 6][3] = rv;
    }
    __syncthreads();
    if (t == 0) {
        float dir = 0.f, colsq = 0.f, ss = 0.f, rec = 0.f;
#pragma unroll
        for (int w = 0; w < 4; ++w) {
            dir += red[w][0]; colsq += red[w][1];
            ss  += red[w][2]; rec   += red[w][3];
        }
        const float n = (float)NN;
        const float avg = (n / (n - 1.f)) * ss - colsq / (n - 1.f);
        out[0] = -(dir + eta[0] * rec + theta[0] * avg);
    }
}

extern "C" void kernel_launch(void* const* d_in, const int* in_sizes, int n_in,
                              void* d_out, int out_size, void* d_ws, size_t ws_size,
                              hipStream_t stream) {
    const float* x     = (const float*)d_in[0];
    const float* L     = (const float*)d_in[1];
    const float* mean  = (const float*)d_in[2];
    const float* oki   = (const float*)d_in[3];
    const int*   know  = (const int*)d_in[4];
    const float* theta = (const float*)d_in[5];
    const float* eta   = (const float*)d_in[6];
    float* out = (float*)d_out;

    char* ws = (char*)d_ws;
    unsigned short* xnF = (unsigned short*)ws;                 // 5,177,344 B
    float* part  = (float*)(ws + 6 * 1024 * 1024);             // NPAIR f32
    float* csbuf = (float*)(ws + 7 * 1024 * 1024);             // PREPB*256 f32
    float* ssbuf = (float*)(ws + 8 * 1024 * 1024);             // PREPB f32
    float* rbuf  = (float*)(ws + 8 * 1024 * 1024 + 4096);      // 256 f32
    const int K = in_sizes[4];

    hipLaunchKernelGGL(prep_kernel,  dim3(PREPB), dim3(256), 0, stream, x, mean, xnF, csbuf, ssbuf);
    hipLaunchKernelGGL(recon_kernel, dim3(256),   dim3(256), 0, stream, x, mean, oki, know, K, rbuf);
    hipLaunchKernelGGL(gram_kernel,  dim3(NPAIR), dim3(256), 0, stream, L, xnF, part);
    hipLaunchKernelGGL(fin_kernel,   dim3(1),     dim3(256), 0, stream, part, csbuf, ssbuf, rbuf, theta, eta, out);
}